// Round 2
// baseline (294.905 us; speedup 1.0000x reference)
//
#include <hip/hip_runtime.h>
#include <math.h>

// Problem constants
#define TT 8
#define BB 128
#define GG 256
#define DD 64
#define NCH 4     // D chunks
#define CF4 4     // float4s per cell per chunk (16 floats)
#define ST 5      // padded LDS stride in float4s (20 dwords -> 2-way/phase, free)

// ws layout: ws[pair*8 + c], c: 0 zdiff, 1 pres, 2 poolc(neg), 3 obj,
//                               4 flow_sq, 5 sum(zp), 6 sum(flow), 7 unused

__device__ inline float wred(float v) {
#pragma unroll
    for (int off = 32; off > 0; off >>= 1) v += __shfl_xor(v, off, 64);
    return v;
}
__device__ inline float dot4(float4 a, float4 b) {
    return a.x * b.x + a.y * b.y + a.z * b.z + a.w * b.w;
}
__device__ inline float4 fabs4(float4 a) {
    return make_float4(fabsf(a.x), fabsf(a.y), fabsf(a.z), fabsf(a.w));
}
__device__ inline float4 max4(float4 a, float4 b) {
    return make_float4(fmaxf(a.x, b.x), fmaxf(a.y, b.y), fmaxf(a.z, b.z), fmaxf(a.w, b.w));
}
__device__ inline float4 scale4(float4 a, float s) {
    return make_float4(a.x * s, a.y * s, a.z * s, a.w * s);
}
__device__ inline float4 sub4(float4 a, float4 b) {
    return make_float4(a.x - b.x, a.y - b.y, a.z - b.z, a.w - b.w);
}

__global__ __launch_bounds__(256) void pair_kernel(const float* __restrict__ zw,
                                                   const float* __restrict__ zp,
                                                   const float* __restrict__ flow,
                                                   float* __restrict__ ws) {
    const int pairIdx = blockIdx.x;            // 0 .. 7*BB-1
    const int t = pairIdx >> 7;                // BB = 128
    const int b = pairIdx & (BB - 1);
    const int tid = threadIdx.x;
    const int gi = tid >> 4, gj = tid & 15;

    __shared__ float4 shW[GG * ST];            // wa = pA*|A| chunk (then reused as-is)
    __shared__ float4 shB[GG * ST];            // raw B chunk, then row-max tmp
    __shared__ float pA[GG], pB[GG], nB[GG];
    __shared__ float bred[8][4];

    const float4* gA = (const float4*)zw + (size_t)(t * BB + b) * 1024;
    const float4* gB = gA + (size_t)BB * 1024;

    const float pAc = zp[(size_t)(t * BB + b) * GG + tid];
    const float pBc = zp[(size_t)((t + 1) * BB + b) * GG + tid];
    pA[tid] = pAc;
    pB[tid] = pBc;

    // 9 wrapped neighbors (jnp.roll semantics) + in-bounds flags (clamped ops)
    int nbc[9];
    bool inb[9];
    {
        int m = 0;
#pragma unroll
        for (int di = -1; di <= 1; di++) {
#pragma unroll
            for (int dj = -1; dj <= 1; dj++) {
                nbc[m] = (((gi + di) & 15) << 4) | ((gj + dj) & 15);
                inb[m] = ((unsigned)(gi + di) < 16u) && ((unsigned)(gj + dj) < 16u);
                m++;
            }
        }
    }
    __syncthreads();

    float zdiff = 0.f, sa = 0.f, sb = 0.f, poolDot = 0.f, poolN = 0.f;
    float dots[9] = {0.f, 0.f, 0.f, 0.f, 0.f, 0.f, 0.f, 0.f, 0.f};

#pragma unroll
    for (int c = 0; c < NCH; c++) {
        float4 aA[CF4], aB[CF4];
#pragma unroll
        for (int q = 0; q < CF4; q++) {
            aA[q] = gA[tid * 16 + c * 4 + q];
            aB[q] = gB[tid * 16 + c * 4 + q];
        }
#pragma unroll
        for (int q = 0; q < CF4; q++) {
            float4 d = sub4(aB[q], aA[q]);
            zdiff += dot4(d, d);
            sa += dot4(aA[q], aA[q]);
            sb += dot4(aB[q], aB[q]);
            dots[4] += dot4(aA[q], aB[q]);          // center dot from registers
            shW[tid * ST + q] = scale4(fabs4(aA[q]), pAc);
            shB[tid * ST + q] = aB[q];
        }
        __syncthreads();

        // neighbor dots: A(center, regs) . B(neighbor, LDS)
#pragma unroll
        for (int k = 0; k < 9; k++) {
            if (k == 4) continue;
            int base = nbc[k] * ST;
#pragma unroll
            for (int q = 0; q < CF4; q++) dots[k] += dot4(aA[q], shB[base + q]);
        }

        // pool pass 1: clamped row-max of wa (own value from registers)
        float4 rm[CF4];
#pragma unroll
        for (int q = 0; q < CF4; q++) rm[q] = scale4(fabs4(aA[q]), pAc);
        if (gj > 0) {
            int base = (tid - 1) * ST;
#pragma unroll
            for (int q = 0; q < CF4; q++) rm[q] = max4(rm[q], shW[base + q]);
        }
        if (gj < 15) {
            int base = (tid + 1) * ST;
#pragma unroll
            for (int q = 0; q < CF4; q++) rm[q] = max4(rm[q], shW[base + q]);
        }
        __syncthreads();   // B-dots done; safe to overwrite shB with row-max tmp
#pragma unroll
        for (int q = 0; q < CF4; q++) shB[tid * ST + q] = rm[q];
        __syncthreads();

        // pool pass 2: clamped col-max, then accumulate pool dot/norm
        float4 sm[CF4];
#pragma unroll
        for (int q = 0; q < CF4; q++) sm[q] = rm[q];
        if (gi > 0) {
            int base = (tid - 16) * ST;
#pragma unroll
            for (int q = 0; q < CF4; q++) sm[q] = max4(sm[q], shB[base + q]);
        }
        if (gi < 15) {
            int base = (tid + 16) * ST;
#pragma unroll
            for (int q = 0; q < CF4; q++) sm[q] = max4(sm[q], shB[base + q]);
        }
#pragma unroll
        for (int q = 0; q < CF4; q++) {
            poolDot += dot4(sm[q], fabs4(aB[q]));
            poolN += dot4(sm[q], sm[q]);
        }
        __syncthreads();   // before next chunk overwrites shW/shB
    }

    // ---- epilogues ----
    nB[tid] = sqrtf(sb);
    __syncthreads();

    // objects
    float prior_n = fmaxf(sqrtf(sa), 1e-8f);
    float sum_sim = 0.f, max_sim = -1e30f;
    bool has = false;
#pragma unroll
    for (int k = 0; k < 9; k++) {
        float nn = fmaxf(nB[nbc[k]], 1e-8f);
        float s = dots[k] / (prior_n * nn);
        if (pB[nbc[k]] > 0.5f) {
            sum_sim += s;
            max_sim = fmaxf(max_sim, s);
            has = true;
        }
    }
    float obj = ((pAc > 0.5f) && has) ? (sum_sim - 5.0f * max_sim) : 0.f;

    // pool
    float na_pool = fmaxf(sqrtf(poolN), 1e-6f);
    float nb_pool = fmaxf(pBc * sqrtf(sb), 1e-6f);
    float poolc = -(pBc * poolDot) / (na_pool * nb_pool) * 0.5f * (pAc + pBc);

    // flow (image t; block t=6 also handles image 7)
    float mx = pAc;
#pragma unroll
    for (int k = 0; k < 9; k++)
        if (k != 4 && inb[k]) mx = fmaxf(mx, pA[nbc[k]]);
    float f = flow[(size_t)(t * BB + b) * GG + tid];
    float fsq = 0.f;
    if (f > 0.5f) { float d = mx - f; fsq = d * d; }
    float szp = pAc, sflow = f;
    if (t == 6) {
        float mxB = pBc;
#pragma unroll
        for (int k = 0; k < 9; k++)
            if (k != 4 && inb[k]) mxB = fmaxf(mxB, pB[nbc[k]]);
        float f7 = flow[(size_t)(7 * BB + b) * GG + tid];
        if (f7 > 0.5f) { float d = mxB - f7; fsq += d * d; }
        szp += pBc;
        sflow += f7;
    }

    // pres triple (t, t+1, t+2) for t <= 5
    float pres = 0.f;
    if (t <= 5) {
        float pC = zp[(size_t)((t + 2) * BB + b) * GG + tid];
        float s02 = pC - pAc;
        float sim = 1.f - s02 * s02;
        float d2 = pC - pBc, d0 = pAc - pBc;
        pres = sim * (d2 * d2 + d0 * d0);
    }

    // ---- block reduce 7 scalars -> private ws slot (no atomics) ----
    float r[7] = {zdiff, pres, poolc, obj, fsq, szp, sflow};
    int w = tid >> 6, lane = tid & 63;
#pragma unroll
    for (int j = 0; j < 7; j++) {
        float rv = wred(r[j]);
        if (lane == 0) bred[j][w] = rv;
    }
    __syncthreads();
    if (tid < 7)
        ws[pairIdx * 8 + tid] = bred[tid][0] + bred[tid][1] + bred[tid][2] + bred[tid][3];
}

__global__ __launch_bounds__(256) void final_kernel(const float* __restrict__ ws,
                                                    const int* __restrict__ gs,
                                                    float* __restrict__ out) {
    const int tid = threadIdx.x;
    __shared__ float bred[7][4];
    float c[7] = {0.f, 0.f, 0.f, 0.f, 0.f, 0.f, 0.f};
    for (int p = tid; p < (TT - 1) * BB; p += 256) {
        const float* r = ws + p * 8;
#pragma unroll
        for (int j = 0; j < 7; j++) c[j] += r[j];
    }
    int w = tid >> 6, lane = tid & 63;
#pragma unroll
    for (int j = 0; j < 7; j++) {
        float rv = wred(c[j]);
        if (lane == 0) bred[j][w] = rv;
    }
    __syncthreads();
    if (tid == 0) {
        float s[7];
#pragma unroll
        for (int j = 0; j < 7; j++) s[j] = bred[j][0] + bred[j][1] + bred[j][2] + bred[j][3];
        float step = (float)gs[0];
        float scale_obj = fminf(1.f, step / 200000.f);
        float scale_flow = fmaxf(0.f, 1.f - step / 100000.f);
        float flow_loss = s[4] + 100.f * fmaxf(0.f, s[5] - s[6]);
        out[0] = s[0]                       // z_what_loss * ADJ_W
               + s[1]                       // z_pres_loss * PRES_W
               + s[2]                       // pool (already negated) * POOL_W
               + s[3] * scale_obj * 10.0f   // objects * OBJ_W
               + flow_loss * scale_flow;    // FLOW_W = 1
    }
}

extern "C" void kernel_launch(void* const* d_in, const int* in_sizes, int n_in,
                              void* d_out, int out_size, void* d_ws, size_t ws_size,
                              hipStream_t stream) {
    const float* zw = (const float*)d_in[0];
    const float* zp = (const float*)d_in[1];
    const float* fl = (const float*)d_in[2];
    const int* gs = (const int*)d_in[3];
    float* ws = (float*)d_ws;

    pair_kernel<<<(TT - 1) * BB, 256, 0, stream>>>(zw, zp, fl, ws);
    final_kernel<<<1, 256, 0, stream>>>(ws, gs, (float*)d_out);
}

// Round 3
// 130.621 us; speedup vs baseline: 2.2577x; 2.2577x over previous
//
#include <hip/hip_runtime.h>
#include <math.h>

// Problem constants
#define TT 8
#define BB 128
#define GG 256
#define DD 64
#define NCH 4     // D chunks
#define CF4 4     // float4s per cell per chunk (16 floats)
#define ST 5      // padded LDS stride in float4s (20 dwords: 8 lanes cover all 32 banks once)

// ws layout: ws[pair*8 + c], c: 0 zdiff, 1 pres, 2 poolc(neg), 3 obj,
//                               4 flow_sq, 5 sum(zp), 6 sum(flow), 7 unused

__device__ inline float wred(float v) {
#pragma unroll
    for (int off = 32; off > 0; off >>= 1) v += __shfl_xor(v, off, 64);
    return v;
}
__device__ inline float dot4(float4 a, float4 b) {
    return a.x * b.x + a.y * b.y + a.z * b.z + a.w * b.w;
}
__device__ inline float4 fabs4(float4 a) {
    return make_float4(fabsf(a.x), fabsf(a.y), fabsf(a.z), fabsf(a.w));
}
__device__ inline float4 max4(float4 a, float4 b) {
    return make_float4(fmaxf(a.x, b.x), fmaxf(a.y, b.y), fmaxf(a.z, b.z), fmaxf(a.w, b.w));
}
__device__ inline float4 scale4(float4 a, float s) {
    return make_float4(a.x * s, a.y * s, a.z * s, a.w * s);
}
__device__ inline float4 sub4(float4 a, float4 b) {
    return make_float4(a.x - b.x, a.y - b.y, a.z - b.z, a.w - b.w);
}

__global__ __launch_bounds__(256) void pair_kernel(const float* __restrict__ zw,
                                                   const float* __restrict__ zp,
                                                   const float* __restrict__ flow,
                                                   float* __restrict__ ws) {
    const int pairIdx = blockIdx.x;            // 0 .. 7*BB-1
    const int t = pairIdx >> 7;                // BB = 128
    const int b = pairIdx & (BB - 1);
    const int tid = threadIdx.x;
    const int gi = tid >> 4, gj = tid & 15;

    __shared__ float4 shW[GG * ST];            // wa = pA*|A| chunk
    __shared__ float4 shB[GG * ST];            // raw B chunk, then row-max tmp
    __shared__ float pA[GG], pB[GG], nB[GG];
    __shared__ float bred[8][4];

    const float4* gA = (const float4*)zw + (size_t)(t * BB + b) * 1024;
    const float4* gB = gA + (size_t)BB * 1024;

    const float pAc = zp[(size_t)(t * BB + b) * GG + tid];
    const float pBc = zp[(size_t)((t + 1) * BB + b) * GG + tid];
    pA[tid] = pAc;
    pB[tid] = pBc;

    // 9 wrapped neighbors (jnp.roll semantics) + in-bounds bitmask (clamped ops)
    int nbc[9];
    unsigned inbM = 0;
    {
        int m = 0;
#pragma unroll
        for (int di = -1; di <= 1; di++) {
#pragma unroll
            for (int dj = -1; dj <= 1; dj++) {
                nbc[m] = (((gi + di) & 15) << 4) | ((gj + dj) & 15);
                if (((unsigned)(gi + di) < 16u) && ((unsigned)(gj + dj) < 16u))
                    inbM |= (1u << m);
                m++;
            }
        }
    }
    __syncthreads();

    float zdiff = 0.f, sa = 0.f, sb = 0.f, poolDot = 0.f, poolN = 0.f;
    float dots[9] = {0.f, 0.f, 0.f, 0.f, 0.f, 0.f, 0.f, 0.f, 0.f};

    // IMPORTANT: unroll 1 — full unroll hoists all chunks' global loads and
    // spills (round-2 post-mortem: VGPR=256, 293 MB scratch writes).
#pragma unroll 1
    for (int c = 0; c < NCH; c++) {
        float4 aA[CF4], aB[CF4];
#pragma unroll
        for (int q = 0; q < CF4; q++) {
            aA[q] = gA[tid * 16 + c * 4 + q];
            aB[q] = gB[tid * 16 + c * 4 + q];
        }
#pragma unroll
        for (int q = 0; q < CF4; q++) {
            float4 d = sub4(aB[q], aA[q]);
            zdiff += dot4(d, d);
            sa += dot4(aA[q], aA[q]);
            sb += dot4(aB[q], aB[q]);
            dots[4] += dot4(aA[q], aB[q]);          // center dot from registers
            shW[tid * ST + q] = scale4(fabs4(aA[q]), pAc);
            shB[tid * ST + q] = aB[q];
        }
        __syncthreads();

        // neighbor dots: A(center, regs) . B(neighbor, LDS)
#pragma unroll
        for (int k = 0; k < 9; k++) {
            if (k == 4) continue;
            int base = nbc[k] * ST;
#pragma unroll
            for (int q = 0; q < CF4; q++) dots[k] += dot4(aA[q], shB[base + q]);
        }

        // pool pass 1: clamped row-max of wa (own value from registers)
        float4 rm[CF4];
#pragma unroll
        for (int q = 0; q < CF4; q++) rm[q] = scale4(fabs4(aA[q]), pAc);
        if (gj > 0) {
            int base = (tid - 1) * ST;
#pragma unroll
            for (int q = 0; q < CF4; q++) rm[q] = max4(rm[q], shW[base + q]);
        }
        if (gj < 15) {
            int base = (tid + 1) * ST;
#pragma unroll
            for (int q = 0; q < CF4; q++) rm[q] = max4(rm[q], shW[base + q]);
        }
        __syncthreads();   // B-dots done; safe to overwrite shB with row-max tmp
#pragma unroll
        for (int q = 0; q < CF4; q++) shB[tid * ST + q] = rm[q];
        __syncthreads();

        // pool pass 2: clamped col-max, then accumulate pool dot/norm
        float4 sm[CF4];
#pragma unroll
        for (int q = 0; q < CF4; q++) sm[q] = rm[q];
        if (gi > 0) {
            int base = (tid - 16) * ST;
#pragma unroll
            for (int q = 0; q < CF4; q++) sm[q] = max4(sm[q], shB[base + q]);
        }
        if (gi < 15) {
            int base = (tid + 16) * ST;
#pragma unroll
            for (int q = 0; q < CF4; q++) sm[q] = max4(sm[q], shB[base + q]);
        }
#pragma unroll
        for (int q = 0; q < CF4; q++) {
            poolDot += dot4(sm[q], fabs4(aB[q]));
            poolN += dot4(sm[q], sm[q]);
        }
        __syncthreads();   // before next chunk overwrites shW/shB
    }

    // ---- epilogues ----
    nB[tid] = sqrtf(sb);
    __syncthreads();

    // objects
    float prior_n = fmaxf(sqrtf(sa), 1e-8f);
    float sum_sim = 0.f, max_sim = -1e30f;
    bool has = false;
#pragma unroll
    for (int k = 0; k < 9; k++) {
        float nn = fmaxf(nB[nbc[k]], 1e-8f);
        float s = dots[k] / (prior_n * nn);
        if (pB[nbc[k]] > 0.5f) {
            sum_sim += s;
            max_sim = fmaxf(max_sim, s);
            has = true;
        }
    }
    float obj = ((pAc > 0.5f) && has) ? (sum_sim - 5.0f * max_sim) : 0.f;

    // pool
    float na_pool = fmaxf(sqrtf(poolN), 1e-6f);
    float nb_pool = fmaxf(pBc * sqrtf(sb), 1e-6f);
    float poolc = -(pBc * poolDot) / (na_pool * nb_pool) * 0.5f * (pAc + pBc);

    // flow (image t; block t=6 also handles image 7)
    float mx = pAc;
#pragma unroll
    for (int k = 0; k < 9; k++)
        if (k != 4 && ((inbM >> k) & 1u)) mx = fmaxf(mx, pA[nbc[k]]);
    float f = flow[(size_t)(t * BB + b) * GG + tid];
    float fsq = 0.f;
    if (f > 0.5f) { float d = mx - f; fsq = d * d; }
    float szp = pAc, sflow = f;
    if (t == 6) {
        float mxB = pBc;
#pragma unroll
        for (int k = 0; k < 9; k++)
            if (k != 4 && ((inbM >> k) & 1u)) mxB = fmaxf(mxB, pB[nbc[k]]);
        float f7 = flow[(size_t)(7 * BB + b) * GG + tid];
        if (f7 > 0.5f) { float d = mxB - f7; fsq += d * d; }
        szp += pBc;
        sflow += f7;
    }

    // pres triple (t, t+1, t+2) for t <= 5
    float pres = 0.f;
    if (t <= 5) {
        float pC = zp[(size_t)((t + 2) * BB + b) * GG + tid];
        float s02 = pC - pAc;
        float sim = 1.f - s02 * s02;
        float d2 = pC - pBc, d0 = pAc - pBc;
        pres = sim * (d2 * d2 + d0 * d0);
    }

    // ---- block reduce 7 scalars -> private ws slot (no atomics) ----
    float r[7] = {zdiff, pres, poolc, obj, fsq, szp, sflow};
    int w = tid >> 6, lane = tid & 63;
#pragma unroll
    for (int j = 0; j < 7; j++) {
        float rv = wred(r[j]);
        if (lane == 0) bred[j][w] = rv;
    }
    __syncthreads();
    if (tid < 7)
        ws[pairIdx * 8 + tid] = bred[tid][0] + bred[tid][1] + bred[tid][2] + bred[tid][3];
}

__global__ __launch_bounds__(256) void final_kernel(const float* __restrict__ ws,
                                                    const int* __restrict__ gs,
                                                    float* __restrict__ out) {
    const int tid = threadIdx.x;
    __shared__ float bred[7][4];
    float c[7] = {0.f, 0.f, 0.f, 0.f, 0.f, 0.f, 0.f};
    for (int p = tid; p < (TT - 1) * BB; p += 256) {
        const float* r = ws + p * 8;
#pragma unroll
        for (int j = 0; j < 7; j++) c[j] += r[j];
    }
    int w = tid >> 6, lane = tid & 63;
#pragma unroll
    for (int j = 0; j < 7; j++) {
        float rv = wred(c[j]);
        if (lane == 0) bred[j][w] = rv;
    }
    __syncthreads();
    if (tid == 0) {
        float s[7];
#pragma unroll
        for (int j = 0; j < 7; j++) s[j] = bred[j][0] + bred[j][1] + bred[j][2] + bred[j][3];
        float step = (float)gs[0];
        float scale_obj = fminf(1.f, step / 200000.f);
        float scale_flow = fmaxf(0.f, 1.f - step / 100000.f);
        float flow_loss = s[4] + 100.f * fmaxf(0.f, s[5] - s[6]);
        out[0] = s[0]                       // z_what_loss * ADJ_W
               + s[1]                       // z_pres_loss * PRES_W
               + s[2]                       // pool (already negated) * POOL_W
               + s[3] * scale_obj * 10.0f   // objects * OBJ_W
               + flow_loss * scale_flow;    // FLOW_W = 1
    }
}

extern "C" void kernel_launch(void* const* d_in, const int* in_sizes, int n_in,
                              void* d_out, int out_size, void* d_ws, size_t ws_size,
                              hipStream_t stream) {
    const float* zw = (const float*)d_in[0];
    const float* zp = (const float*)d_in[1];
    const float* fl = (const float*)d_in[2];
    const int* gs = (const int*)d_in[3];
    float* ws = (float*)d_ws;

    pair_kernel<<<(TT - 1) * BB, 256, 0, stream>>>(zw, zp, fl, ws);
    final_kernel<<<1, 256, 0, stream>>>(ws, gs, (float*)d_out);
}